// Round 1
// baseline (80.519 us; speedup 1.0000x reference)
//
#include <hip/hip_runtime.h>

// NMU forward: y[b, o] = prod_d ( clip(M[d,o],0,1) * x[b,d] + (1 - clip(M[d,o],0,1)) )
// B=16384, D=256, O=32, all fp32.
//
// Mapping: lane o = tid & 31 (output column), slot = tid >> 5 (row group).
// Each thread computes R rows for its fixed o. M column values are register-
// cached in chunks of DC=32 d's (coalesced global loads: lanes 0..31 read
// consecutive addresses), amortized over R rows. x[row][d] is loaded as
// float4 directly from global: all lanes with the same row hit the same
// address -> HW broadcast, each x byte fetched once from HBM grid-wide.

constexpr int D  = 256;
constexpr int O  = 32;
constexpr int SLOTS = 8;               // 256 threads / 32 lanes-per-o-group
constexpr int R  = 4;                  // rows per thread
constexpr int ROWS_PER_BLOCK = SLOTS * R;  // 32
constexpr int DC = 32;                 // d-chunk register-cached per thread

__global__ __launch_bounds__(256) void nmu_fwd_kernel(
    const float* __restrict__ x, const float* __restrict__ M,
    float* __restrict__ y)
{
    const int o    = threadIdx.x & 31;
    const int slot = threadIdx.x >> 5;
    const int row0 = blockIdx.x * ROWS_PER_BLOCK + slot;

    float prod[R];
#pragma unroll
    for (int i = 0; i < R; ++i) prod[i] = 1.0f;

#pragma unroll
    for (int dc = 0; dc < D; dc += DC) {
        // Register-cache M_hat and (1 - M_hat) for this d-chunk (my column o).
        float mh[DC], om[DC];
#pragma unroll
        for (int j = 0; j < DC; ++j) {
            float v = M[(dc + j) * O + o];
            v = __builtin_amdgcn_fmed3f(v, 0.0f, 1.0f);   // clamp to [0,1]
            mh[j] = v;
            om[j] = 1.0f - v;
        }

#pragma unroll
        for (int i = 0; i < R; ++i) {
            const int row = row0 + i * SLOTS;
            const float4* xp = reinterpret_cast<const float4*>(x + row * D + dc);
            float p = prod[i];
#pragma unroll
            for (int q = 0; q < DC / 4; ++q) {
                float4 xv = xp[q];
                float t0 = fmaf(xv.x, mh[4*q+0], om[4*q+0]);
                float t1 = fmaf(xv.y, mh[4*q+1], om[4*q+1]);
                float t2 = fmaf(xv.z, mh[4*q+2], om[4*q+2]);
                float t3 = fmaf(xv.w, mh[4*q+3], om[4*q+3]);
                p = p * ((t0 * t1) * (t2 * t3));  // short dep chain: 1 mul on p per 4 d
            }
            prod[i] = p;
        }
    }

#pragma unroll
    for (int i = 0; i < R; ++i) {
        const int row = row0 + i * SLOTS;
        y[row * O + o] = prod[i];   // lanes 0..31 -> 128B contiguous per row
    }
}

extern "C" void kernel_launch(void* const* d_in, const int* in_sizes, int n_in,
                              void* d_out, int out_size, void* d_ws, size_t ws_size,
                              hipStream_t stream) {
    const float* x = (const float*)d_in[0];   // [B, 256]
    const float* M = (const float*)d_in[1];   // [256, 32]
    float* y = (float*)d_out;                 // [B, 32]
    const int B = in_sizes[0] / D;            // 16384
    dim3 grid(B / ROWS_PER_BLOCK);            // 512 blocks, 256 thr = 2 blocks/CU
    nmu_fwd_kernel<<<grid, 256, 0, stream>>>(x, M, y);
}